// Round 1
// baseline (218.087 us; speedup 1.0000x reference)
//
#include <hip/hip_runtime.h>
#include <hip/hip_bf16.h>
#include <cstddef>

// Problem constants (from reference setup_inputs)
#define BB 16
#define CC 192
#define HH 64
#define WW 64
#define LL 4096   // H*W
#define DTR 12    // dt_rank
#define KK 14     // dt_rank + 2*d_state, d_state = 1

// ---------------------------------------------------------------------------
// K1: depthwise 5x5 conv (SAME, zero pad) + bias + SiLU
// one block per (b,c) plane; 68x68 halo tile in LDS
// ---------------------------------------------------------------------------
__global__ __launch_bounds__(256) void conv_silu_kernel(
    const float* __restrict__ x, const float* __restrict__ cw,
    const float* __restrict__ cb, float* __restrict__ xs) {
  const int bc = blockIdx.x;           // b*CC + c
  const int c = bc % CC;
  const int tid = threadIdx.x;
  __shared__ float sm[68 * 68];

  const float* xp = x + (size_t)bc * LL;
  // halo load (zero padding outside)
  for (int i = tid; i < 68 * 68; i += 256) {
    int r = i / 68;
    int q = i - r * 68;
    int gy = r - 2, gx = q - 2;
    float v = 0.f;
    if ((unsigned)gy < 64u && (unsigned)gx < 64u) v = xp[gy * 64 + gx];
    sm[i] = v;
  }
  float w[25];
#pragma unroll
  for (int k = 0; k < 25; ++k) w[k] = cw[c * 25 + k];
  const float bias = cb[c];
  __syncthreads();

  float* op = xs + (size_t)bc * LL;
#pragma unroll
  for (int j = 0; j < 16; ++j) {
    int p = tid + j * 256;
    int oy = p >> 6, ox = p & 63;
    float acc = bias;
#pragma unroll
    for (int ky = 0; ky < 5; ++ky)
#pragma unroll
      for (int kx = 0; kx < 5; ++kx)
        acc += sm[(oy + ky) * 68 + ox + kx] * w[ky * 5 + kx];
    // SiLU
    float s = acc / (1.f + __expf(-acc));
    op[p] = s;
  }
}

// ---------------------------------------------------------------------------
// K2: x_dbl = x_proj_w @ xs  (reduce over C), then
//     delta[b,c,l] = softplus(dt_w[c,:]·dts[b,:,l] + dt_b[c])  for all c
// block = (l-tile of 64, b); 256 threads = 4 waves, each wave reduces 48 ch.
// ---------------------------------------------------------------------------
__global__ __launch_bounds__(256) void proj_kernel(
    const float* __restrict__ xs, const float* __restrict__ xpw,
    const float* __restrict__ dtw, const float* __restrict__ dtb,
    float* __restrict__ delta, float* __restrict__ Bsg,
    float* __restrict__ Csg) {
  const int b = blockIdx.y;
  const int l0 = blockIdx.x * 64;
  const int tid = threadIdx.x;
  const int lane = tid & 63;
  const int g = tid >> 6;  // wave id, 0..3

  __shared__ float part[KK][4][64];
  __shared__ float dts[KK][64];

  // phase 1: channel reduction, 48 channels per wave
  float acc[KK];
#pragma unroll
  for (int k = 0; k < KK; ++k) acc[k] = 0.f;
  const int c0 = g * 48;
  const float* xsb = xs + (size_t)b * CC * LL + l0 + lane;
  for (int cc = 0; cc < 48; ++cc) {
    int c = c0 + cc;
    float v = xsb[(size_t)c * LL];
#pragma unroll
    for (int k = 0; k < KK; ++k) acc[k] += xpw[k * CC + c] * v;
  }
#pragma unroll
  for (int k = 0; k < KK; ++k) part[k][g][lane] = acc[k];
  __syncthreads();

  // reduce 4 partials -> dts
  for (int idx = tid; idx < KK * 64; idx += 256) {
    int k = idx >> 6, ln = idx & 63;
    dts[k][ln] = part[k][0][ln] + part[k][1][ln] + part[k][2][ln] + part[k][3][ln];
  }
  __syncthreads();

  if (tid < 64) {
    Bsg[(size_t)b * LL + l0 + tid] = dts[12][tid];
    Csg[(size_t)b * LL + l0 + tid] = dts[13][tid];
  }

  // phase 2: dt projection + softplus for all 192 channels (c uniform per wave)
  float dvals[DTR];
#pragma unroll
  for (int r = 0; r < DTR; ++r) dvals[r] = dts[r][lane];
  float* dptr = delta + (size_t)b * CC * LL + l0 + lane;
  for (int c = g; c < CC; c += 4) {
    float z = dtb[c];
#pragma unroll
    for (int r = 0; r < DTR; ++r) z += dtw[c * DTR + r] * dvals[r];
    float sp = (z > 15.f) ? z : __logf(1.f + __expf(z));
    dptr[(size_t)c * LL] = sp;
  }
}

// ---------------------------------------------------------------------------
// K3: selective scan per (b,c) sequence of length L=4096.
// h_t = exp(delta_t*A_c)*h_{t-1} + delta_t*Bs_t*xs_t;  y = h*Cs + xs*Ds
// block = 256 threads x 16 contiguous elems. Affine-composition block scan.
// ---------------------------------------------------------------------------
__global__ __launch_bounds__(256) void scan_kernel(
    const float* __restrict__ xs, const float* __restrict__ delta,
    const float* __restrict__ Bsg, const float* __restrict__ Csg,
    const float* __restrict__ A_logs, const float* __restrict__ Ds,
    float* __restrict__ y) {
  const int bc = blockIdx.x;
  const int b = bc / CC;
  const int c = bc - b * CC;
  const int tid = threadIdx.x;
  const int lane = tid & 63;
  const int wid = tid >> 6;

  const float Ac = -__expf(A_logs[c]);  // d_state = 1
  const float Dc = Ds[c];

  const float* dp = delta + (size_t)bc * LL;
  const float* xp = xs + (size_t)bc * LL;
  const float* Bp = Bsg + (size_t)b * LL;
  const float* Cp = Csg + (size_t)b * LL;
  float* yp = y + (size_t)bc * LL;

  const int base = tid * 16;

  float av[16], bv[16], xd[16];
  float aggA = 1.f, aggB = 0.f;

  // phase 1: per-element terms + local sequential composition
#pragma unroll
  for (int j = 0; j < 4; ++j) {
    float4 d4 = *(const float4*)(dp + base + j * 4);
    float4 x4 = *(const float4*)(xp + base + j * 4);
    float4 B4 = *(const float4*)(Bp + base + j * 4);
    float dd[4] = {d4.x, d4.y, d4.z, d4.w};
    float xx[4] = {x4.x, x4.y, x4.z, x4.w};
    float bb[4] = {B4.x, B4.y, B4.z, B4.w};
#pragma unroll
    for (int q = 0; q < 4; ++q) {
      int i = j * 4 + q;
      float a = __expf(dd[q] * Ac);
      float be = dd[q] * bb[q] * xx[q];
      av[i] = a;
      bv[i] = be;
      xd[i] = xx[q] * Dc;
      // compose: (aggA,aggB) then (a,be)
      aggA = a * aggA;
      aggB = a * aggB + be;
    }
  }

  // phase 2: block-exclusive scan of (aggA, aggB)
  // wave-level inclusive scan via shfl_up
  float incA = aggA, incB = aggB;
#pragma unroll
  for (int s = 1; s < 64; s <<= 1) {
    float pA = __shfl_up(incA, (unsigned)s, 64);
    float pB = __shfl_up(incB, (unsigned)s, 64);
    if (lane >= s) {
      // (pA,pB) applied first, then (incA,incB)
      incB = incA * pB + incB;
      incA = incA * pA;
    }
  }
  __shared__ float wA[4], wB[4];
  if (lane == 63) {
    wA[wid] = incA;
    wB[wid] = incB;
  }
  __syncthreads();
  // wave prefix (waves before wid)
  float wpA = 1.f, wpB = 0.f;
  for (int w = 0; w < wid; ++w) {
    float a2 = wA[w], b2 = wB[w];
    // wp then wave w:  (a2*wpA, a2*wpB + b2)
    wpB = a2 * wpB + b2;
    wpA = a2 * wpA;
  }
  // exclusive within wave
  float eA = __shfl_up(incA, 1u, 64);
  float eB = __shfl_up(incB, 1u, 64);
  if (lane == 0) { eA = 1.f; eB = 0.f; }
  // total prefix = wp then excl
  float preB = eA * wpB + eB;
  // (preA not needed since h_init = 0)

  // phase 3: apply prefix, emit y
  float h = preB;
#pragma unroll
  for (int j = 0; j < 4; ++j) {
    float4 C4 = *(const float4*)(Cp + base + j * 4);
    float cvals[4] = {C4.x, C4.y, C4.z, C4.w};
    float4 o;
    float ov[4];
#pragma unroll
    for (int q = 0; q < 4; ++q) {
      int i = j * 4 + q;
      h = av[i] * h + bv[i];
      ov[q] = h * cvals[q] + xd[i];
    }
    o.x = ov[0]; o.y = ov[1]; o.z = ov[2]; o.w = ov[3];
    *(float4*)(yp + base + j * 4) = o;
  }
}

// ---------------------------------------------------------------------------
extern "C" void kernel_launch(void* const* d_in, const int* in_sizes, int n_in,
                              void* d_out, int out_size, void* d_ws,
                              size_t ws_size, hipStream_t stream) {
  const float* x        = (const float*)d_in[0];
  const float* conv_w   = (const float*)d_in[1];
  const float* conv_b   = (const float*)d_in[2];
  const float* x_proj_w = (const float*)d_in[3];
  const float* dt_w     = (const float*)d_in[4];
  const float* dt_b     = (const float*)d_in[5];
  const float* A_logs   = (const float*)d_in[6];
  const float* Ds       = (const float*)d_in[7];
  float* out = (float*)d_out;

  char* ws = (char*)d_ws;
  const size_t plane_bytes = (size_t)BB * CC * LL * sizeof(float);  // 50331648
  float* xs    = (float*)ws;
  float* delta = (float*)(ws + plane_bytes);
  float* Bsg   = (float*)(ws + 2 * plane_bytes);
  float* Csg   = (float*)(ws + 2 * plane_bytes + (size_t)BB * LL * sizeof(float));

  conv_silu_kernel<<<dim3(BB * CC), 256, 0, stream>>>(x, conv_w, conv_b, xs);
  proj_kernel<<<dim3(LL / 64, BB), 256, 0, stream>>>(xs, x_proj_w, dt_w, dt_b,
                                                     delta, Bsg, Csg);
  scan_kernel<<<dim3(BB * CC), 256, 0, stream>>>(xs, delta, Bsg, Csg, A_logs,
                                                 Ds, out);
}